// Round 7
// baseline (787.445 us; speedup 1.0000x reference)
//
#include <hip/hip_runtime.h>

typedef unsigned short u16;
typedef unsigned int u32;
typedef __attribute__((ext_vector_type(4)))  int  i32x4;
typedef __attribute__((ext_vector_type(16))) int  i32x16;
typedef __attribute__((ext_vector_type(16))) char i8x16;

#define NPTS 131072
#define DIM  256
#define KC   2048

// 3-level fixed point: v = S1*q1 + S2*q2 + S3*q3 + eps, |eps| <= S3/2 ~ 4.8e-7
// Ratio 254 => |q2|,|q3| <= 127 by construction (|r1| <= S1/2 -> r1*IS2 <= 127):
// no clamps needed past level 1. S1*S3 == S2*S2 shares one accumulator for
// q2q2, q1q3, q3q1.
constexpr float S1  = 0.0625f;                 // 127*S1 = 7.94 >> max|N(0,1)|
constexpr float S2  = S1 / 254.0f;
constexpr float S3  = S2 * S2 / S1;            // = S2/254
constexpr float IS1 = 16.0f;
constexpr float IS2 = 4064.0f;                 // 254/S1
constexpr float IS3 = 1.0f / S3;
constexpr float W_A = S1 * S1;
// epilogue in W_A units: score' = 0.5*csq/W_A - (A + (B*254+C)/254^2)
constexpr float R3  = 1.0f / 64516.0f;

__device__ inline void quant3(float v, char& q1, char& q2, char& q3) {
    float a = fminf(fmaxf(rintf(v * IS1), -127.f), 127.f);
    float r1 = fmaf(-a, S1, v);                // exact (pow2 scale)
    float b = rintf(r1 * IS2);                 // |b| <= 127 guaranteed
    float r2 = fmaf(-b, S2, r1);
    float c = rintf(r2 * IS3);                 // |c| <= 127 guaranteed
    q1 = (char)a; q2 = (char)b; q3 = (char)c;
}

// global -> LDS direct DMA, 16B per lane (wave-uniform base + lane*16)
#define GLD16(gsrc, ldst) \
    __builtin_amdgcn_global_load_lds( \
        (const __attribute__((address_space(1))) void*)(gsrc), \
        (__attribute__((address_space(3))) void*)(ldst), 16, 0, 0)

// ---------------------------------------------------------------------------
// Centroid prep: 3-level i8 split in MFMA-A-fragment order + scaled 0.5||c||^2.
// Per tile g (32 centroids): chunk s = dim/16, addr = ((g*16+s)*32+row)*16+b.
// Level l at byte offset l*KC*DIM. Sub-tile (g, half h) = bytes
// [g*8192 + h*4096, +4096) of each level -- contiguous, so no layout change.
// Also zeroes hist (blocks 0..7) and sums (all 512 blocks, 1 float4/thread).
// ---------------------------------------------------------------------------
__global__ void cprep_kernel(const float* __restrict__ cen,
                             char* __restrict__ c_q,
                             float* __restrict__ c_sq,
                             int* __restrict__ hist,
                             float* __restrict__ sums) {
    if (blockIdx.x < 8) hist[blockIdx.x * 256 + threadIdx.x] = 0;
    float4 z = {0.f, 0.f, 0.f, 0.f};
    ((float4*)sums)[blockIdx.x * 256 + threadIdx.x] = z;   // 512*256 float4 = KC*DIM
    const int lane = threadIdx.x & 63;
    const int wv   = threadIdx.x >> 6;
    const int n    = blockIdx.x * 4 + wv;               // centroid row
    float4 v = ((const float4*)(cen + (size_t)n * DIM))[lane];  // dims lane*4..+3
    float ss = v.x * v.x + v.y * v.y + v.z * v.z + v.w * v.w;
    float fv[4] = {v.x, v.y, v.z, v.w};
    char q1[4], q2[4], q3[4];
#pragma unroll
    for (int j = 0; j < 4; ++j) quant3(fv[j], q1[j], q2[j], q3[j]);
    const int g = n >> 5, r32 = n & 31;
    const int s = lane >> 2;                             // chunk = dim/16
    const size_t base = ((size_t)((g * 16 + s) * 32 + r32)) * 16 + (lane & 3) * 4;
    u32 p1 = (u32)(unsigned char)q1[0] | ((u32)(unsigned char)q1[1] << 8) |
             ((u32)(unsigned char)q1[2] << 16) | ((u32)(unsigned char)q1[3] << 24);
    u32 p2 = (u32)(unsigned char)q2[0] | ((u32)(unsigned char)q2[1] << 8) |
             ((u32)(unsigned char)q2[2] << 16) | ((u32)(unsigned char)q2[3] << 24);
    u32 p3 = (u32)(unsigned char)q3[0] | ((u32)(unsigned char)q3[1] << 8) |
             ((u32)(unsigned char)q3[2] << 16) | ((u32)(unsigned char)q3[3] << 24);
    *(u32*)(c_q + base) = p1;
    *(u32*)(c_q + (size_t)KC * DIM + base) = p2;
    *(u32*)(c_q + (size_t)2 * KC * DIM + base) = p3;
#pragma unroll
    for (int off = 32; off > 0; off >>= 1) ss += __shfl_xor(ss, off);
    if (lane == 0) c_sq[n] = 0.5f * ss / W_A;            // pre-scaled for epilogue
}

// ---------------------------------------------------------------------------
// Assignment: per wave 32 points x all 2048 centroids, 6 i8 MFMAs per k-tile.
// K-split 12KB sub-tiles (32 cen x 128 dims x 3 levels), double-buffered in
// 24KB LDS -> 4 blocks/CU; launch_bounds(256,4) caps total regs at 128
// (16 waves/CU). acc persists across a group's two K-halves.
// ---------------------------------------------------------------------------
__global__ __launch_bounds__(256, 4) void assign_kernel(
    const float* __restrict__ x, const char* __restrict__ c_q,
    const float* __restrict__ c_sq, int* __restrict__ assigns,
    int* __restrict__ hist) {
    __shared__ char lds_c[2 * 12288];   // buf: [q1 4KB][q2 4KB][q3 4KB] x 2

    const int tid  = threadIdx.x;
    const int lane = tid & 63;
    const int wv   = tid >> 6;
    const int l31  = lane & 31;
    const int kh   = lane >> 5;         // 16-dim half of the 32-dim k-tile

    // ---- quantize this lane's point (dims kt*32+kh*16 .. +15 per kt) ----
    const int m = blockIdx.x * 128 + wv * 32 + l31;
    const float4* xr = (const float4*)(x + (size_t)m * DIM);
    i8x16 xq1[8], xq2[8], xq3[8];
#pragma unroll
    for (int kt = 0; kt < 8; ++kt) {
        float tmp[16];
#pragma unroll
        for (int j = 0; j < 4; ++j) {
            float4 f = xr[kt * 8 + kh * 4 + j];
            tmp[j * 4 + 0] = f.x; tmp[j * 4 + 1] = f.y;
            tmp[j * 4 + 2] = f.z; tmp[j * 4 + 3] = f.w;
        }
        i8x16 v1, v2, v3;
#pragma unroll
        for (int j = 0; j < 16; ++j) {
            char a, b, c;
            quant3(tmp[j], a, b, c);
            v1[j] = a; v2[j] = b; v3[j] = c;
        }
        xq1[kt] = v1; xq2[kt] = v2; xq3[kt] = v3;
    }

    const float4* csq4 = (const float4*)c_sq;
    float best = 3.4e38f;
    int bidx = 0;

    const char* cl2 = c_q + (size_t)KC * DIM;
    const char* cl3 = c_q + (size_t)2 * KC * DIM;

    // DMA one 12KB sub-tile (3 levels x 4KB); 3 GLD16 per thread
#define DMA_SUB(dstbuf, srcoff) do { \
        char* _d = lds_c + (dstbuf) * 12288; \
        const size_t _o = (srcoff); \
        GLD16(c_q + _o + tid * 16, _d + tid * 16); \
        GLD16(cl2 + _o + tid * 16, _d + 4096 + tid * 16); \
        GLD16(cl3 + _o + tid * 16, _d + 8192 + tid * 16); \
    } while (0)

    // 6 MFMAs for local k-step ktl (0..3) from buffer b, x-frag index xi
#define KSTEP(b, ktl, xi) do { \
        const char* _cb = lds_c + (b) * 12288; \
        const int _off = (((ktl) * 2 + kh) * 32 + l31) * 16; \
        i32x4 c1 = __builtin_bit_cast(i32x4, *(const i8x16*)(_cb + _off)); \
        i32x4 c2 = __builtin_bit_cast(i32x4, *(const i8x16*)(_cb + 4096 + _off)); \
        i32x4 c3 = __builtin_bit_cast(i32x4, *(const i8x16*)(_cb + 8192 + _off)); \
        i32x4 x1 = __builtin_bit_cast(i32x4, xq1[xi]); \
        i32x4 x2 = __builtin_bit_cast(i32x4, xq2[xi]); \
        i32x4 x3 = __builtin_bit_cast(i32x4, xq3[xi]); \
        accA = __builtin_amdgcn_mfma_i32_32x32x32_i8(c1, x1, accA, 0, 0, 0); \
        accB = __builtin_amdgcn_mfma_i32_32x32x32_i8(c1, x2, accB, 0, 0, 0); \
        accC = __builtin_amdgcn_mfma_i32_32x32x32_i8(c2, x2, accC, 0, 0, 0); \
        accB = __builtin_amdgcn_mfma_i32_32x32x32_i8(c2, x1, accB, 0, 0, 0); \
        accC = __builtin_amdgcn_mfma_i32_32x32x32_i8(c1, x3, accC, 0, 0, 0); \
        accC = __builtin_amdgcn_mfma_i32_32x32x32_i8(c3, x1, accC, 0, 0, 0); \
    } while (0)

    DMA_SUB(0, 0);                       // prologue: (g=0, h=0)

    int buf = 0;
    for (int g = 0; g < 64; ++g) {
        // ---- phase 0: k-dims 0..127 ----
        __syncthreads();                 // sub (g,0) in buf valid
        DMA_SUB(buf ^ 1, (size_t)g * 8192 + 4096);      // prefetch (g,1)
        i32x16 accA = {}, accB = {}, accC = {};
        KSTEP(buf, 0, 0); KSTEP(buf, 1, 1); KSTEP(buf, 2, 2); KSTEP(buf, 3, 3);
        buf ^= 1;
        // ---- phase 1: k-dims 128..255 ----
        __syncthreads();                 // sub (g,1) in buf valid
        if (g < 63) DMA_SUB(buf ^ 1, (size_t)(g + 1) * 8192);  // prefetch (g+1,0)
        KSTEP(buf, 0, 4); KSTEP(buf, 1, 5); KSTEP(buf, 2, 6); KSTEP(buf, 3, 7);
        buf ^= 1;

        // epilogue: score' = csq_s - (A + (B*254+C)/254^2)
        // D row = (reg&3) + 8*(reg>>2) + 4*kh
#pragma unroll
        for (int bq = 0; bq < 4; ++bq) {
            float4 cs = csq4[g * 8 + 2 * bq + kh];
            const int n0 = g * 32 + 8 * bq + 4 * kh;
            float csa[4] = {cs.x, cs.y, cs.z, cs.w};
#pragma unroll
            for (int r = 0; r < 4; ++r) {
                const int idx = bq * 4 + r;
                int bc = __mul24(accB[idx], 254) + accC[idx];
                float dot = fmaf((float)bc, R3, (float)accA[idx]);
                float v = csa[r] - dot;
                if (v < best) { best = v; bidx = n0 + r; }
            }
        }
    }

    // merge the lane pair holding the other 16 centroid rows for point m
    float oval = __shfl_xor(best, 32);
    int   oidx = __shfl_xor(bidx, 32);
    if (oval < best || (oval == best && oidx < bidx)) { best = oval; bidx = oidx; }
    if (lane < 32) {
        assigns[m] = bidx;
        atomicAdd(&hist[bidx], 1);
    }
#undef DMA_SUB
#undef KSTEP
}

// Exclusive prefix sum over KC=2048 counts; one block of 256 threads x 8 each.
__global__ void scan_kernel(const int* __restrict__ hist,
                            int* __restrict__ base_,
                            int* __restrict__ cursor) {
    __shared__ int tmp[256];
    const int tid = threadIdx.x;
    int v[8], s = 0;
#pragma unroll
    for (int j = 0; j < 8; ++j) { v[j] = hist[tid * 8 + j]; s += v[j]; }
    tmp[tid] = s;
    __syncthreads();
    for (int off = 1; off < 256; off <<= 1) {
        int t = (tid >= off) ? tmp[tid - off] : 0;
        __syncthreads();
        tmp[tid] += t;
        __syncthreads();
    }
    int ex = tmp[tid] - s;
#pragma unroll
    for (int j = 0; j < 8; ++j) {
        base_[tid * 8 + j] = ex;
        cursor[tid * 8 + j] = ex;
        ex += v[j];
    }
}

__global__ void reorder_kernel(const int* __restrict__ assigns,
                               int* __restrict__ cursor,
                               int* __restrict__ order) {
    const int p = blockIdx.x * 256 + threadIdx.x;
    const int a = assigns[p];
    int pos = atomicAdd(&cursor[a], 1);
    order[pos] = p;
}

// ---------------------------------------------------------------------------
// Skew-immune segmented reduce: each block owns 256 consecutive rows of the
// SORTED order array; thread t owns dim t (coalesced 1KB row reads). Flush to
// sums[] with atomics only at cluster boundaries (block-uniform branches).
// ---------------------------------------------------------------------------
__global__ void reduce_kernel(const float* __restrict__ x,
                              const int* __restrict__ order,
                              const int* __restrict__ assigns,
                              float* __restrict__ sums) {
    const int tid = threadIdx.x;
    const int r0 = blockIdx.x * 256;
    float acc = 0.f;
    int cur = assigns[order[r0]];
    for (int r = 0; r < 256; r += 4) {
        int p0 = order[r0 + r + 0], p1 = order[r0 + r + 1];
        int p2 = order[r0 + r + 2], p3 = order[r0 + r + 3];
        float v0 = x[(size_t)p0 * DIM + tid];
        float v1 = x[(size_t)p1 * DIM + tid];
        float v2 = x[(size_t)p2 * DIM + tid];
        float v3 = x[(size_t)p3 * DIM + tid];
        int a0 = assigns[p0], a1 = assigns[p1], a2 = assigns[p2], a3 = assigns[p3];
        if (a0 != cur) { unsafeAtomicAdd(&sums[(size_t)cur * DIM + tid], acc); acc = 0.f; cur = a0; }
        acc += v0;
        if (a1 != cur) { unsafeAtomicAdd(&sums[(size_t)cur * DIM + tid], acc); acc = 0.f; cur = a1; }
        acc += v1;
        if (a2 != cur) { unsafeAtomicAdd(&sums[(size_t)cur * DIM + tid], acc); acc = 0.f; cur = a2; }
        acc += v2;
        if (a3 != cur) { unsafeAtomicAdd(&sums[(size_t)cur * DIM + tid], acc); acc = 0.f; cur = a3; }
        acc += v3;
    }
    unsafeAtomicAdd(&sums[(size_t)cur * DIM + tid], acc);
}

__global__ void finalize_kernel(const float* __restrict__ sums,
                                const int* __restrict__ hist,
                                const float* __restrict__ cen,
                                float* __restrict__ out) {
    const int id = blockIdx.x * 256 + threadIdx.x;   // KC*64 items
    const int k = id >> 6;
    const int cnt = hist[k];
    float4 s = ((const float4*)sums)[id];
    float4 c = ((const float4*)cen)[id];
    float4 o;
    if (cnt > 0) {
        float r = 1.0f / (float)cnt;
        o.x = s.x * r; o.y = s.y * r; o.z = s.z * r; o.w = s.w * r;
    } else {
        o = c;
    }
    ((float4*)out)[id] = o;
}

extern "C" void kernel_launch(void* const* d_in, const int* in_sizes, int n_in,
                              void* d_out, int out_size, void* d_ws, size_t ws_size,
                              hipStream_t stream) {
    (void)in_sizes; (void)n_in; (void)out_size; (void)ws_size;
    const float* x   = (const float*)d_in[0];
    const float* cen = (const float*)d_in[1];
    float* out = (float*)d_out;

    char* ws = (char*)d_ws;
    size_t off = 0;
    char* c_q = (char*)(ws + off);           off += (size_t)3 * KC * DIM;      // 1.5MB
    float* c_sq = (float*)(ws + off);        off += (size_t)KC * 4;            // 8KB
    int* assigns = (int*)(ws + off);         off += (size_t)NPTS * 4;          // 512KB
    int* hist = (int*)(ws + off);            off += (size_t)KC * 4;            // 8KB
    int* base_ = (int*)(ws + off);           off += (size_t)KC * 4;            // 8KB
    int* cursor = (int*)(ws + off);          off += (size_t)KC * 4;            // 8KB
    int* order = (int*)(ws + off);           off += (size_t)NPTS * 4;          // 512KB
    float* sums = (float*)(ws + off);        off += (size_t)KC * DIM * 4;      // 2MB

    cprep_kernel<<<KC / 4, 256, 0, stream>>>(cen, c_q, c_sq, hist, sums);
    assign_kernel<<<NPTS / 128, 256, 0, stream>>>(x, c_q, c_sq, assigns, hist);
    scan_kernel<<<1, 256, 0, stream>>>(hist, base_, cursor);
    reorder_kernel<<<NPTS / 256, 256, 0, stream>>>(assigns, cursor, order);
    reduce_kernel<<<NPTS / 256, 256, 0, stream>>>(x, order, assigns, sums);
    finalize_kernel<<<KC * 64 / 256, 256, 0, stream>>>(sums, hist, cen, out);
}